// Round 16
// baseline (324.511 us; speedup 1.0000x reference)
//
#include <hip/hip_runtime.h>

#define NN 20000
#define EE 660000      // 640000 + 20000 self loops
#define GG 64
#define FIN 114
#define H1 3
#define F1 342         // H1*FIN
#define D2 128
#define NEG 0.2f

typedef __attribute__((ext_vector_type(8))) short short8v;
typedef __attribute__((ext_vector_type(4))) float f32x4;
typedef unsigned short ushort_t;
typedef __attribute__((ext_vector_type(4))) unsigned short ushort4v;

__device__ inline unsigned fenc(float f) {
    unsigned u = __float_as_uint(f);
    return (u & 0x80000000u) ? ~u : (u | 0x80000000u);
}
__device__ inline float fdec(unsigned u) {
    return (u & 0x80000000u) ? __uint_as_float(u & 0x7FFFFFFFu) : __uint_as_float(~u);
}
__device__ inline float lrelu(float x) { return x > 0.f ? x : NEG * x; }

// fp32 -> bf16 hi (truncate) + bf16 lo (RNE of residual); x ≈ hi + lo to ~2^-17
__device__ inline void split2(float x, ushort_t& hi, ushort_t& lo) {
    unsigned u = __float_as_uint(x);
    unsigned uh = u & 0xFFFF0000u;
    hi = (ushort_t)(uh >> 16);
    float r = x - __uint_as_float(uh);
    unsigned v = __float_as_uint(r);
    unsigned vh = (v + 0x7FFFu + ((v >> 16) & 1u)) & 0xFFFF0000u;
    lo = (ushort_t)(vh >> 16);
}

// ===== fold a_src/a_dst through W1 =====
__global__ void k_wa(const float* __restrict__ W1, const float* __restrict__ aS,
                     const float* __restrict__ aD, float* __restrict__ was,
                     float* __restrict__ wad) {
    int tid = blockIdx.x * 256 + threadIdx.x;
    if (tid >= 2 * FIN * H1) return;
    int which = tid >= FIN * H1;
    int i = which ? tid - FIN * H1 : tid;
    int k = i / H1, h = i % H1;
    const float* a = which ? aD : aS;
    float s = 0.f;
    for (int d = 0; d < FIN; d++) s += W1[k * F1 + h * FIN + d] * a[h * FIN + d];
    (which ? wad : was)[i] = s;
}

// ===== W1 prep: W1T[h][c][k] hi/lo bf16, c,k in [0,128) zero-padded =====
__global__ void k_prep1m(const float* __restrict__ W1, ushort_t* __restrict__ W1Th,
                         ushort_t* __restrict__ W1Tl) {
    int tid = blockIdx.x * 256 + threadIdx.x;
    if (tid >= H1 * 128 * 128) return;
    int h = tid / (128 * 128);
    int rem = tid & (128 * 128 - 1);
    int c = rem >> 7, k = rem & 127;
    float v = (c < FIN && k < FIN) ? W1[k * F1 + h * FIN + c] : 0.f;
    ushort_t hi, lo;
    split2(v, hi, lo);
    W1Th[tid] = hi;
    W1Tl[tid] = lo;
}

// ===== W2 prep: W2T[c][hk] hi/lo bf16, hk = h*128+k (k zero-padded) =====
__global__ void k_prep2m(const float* __restrict__ W2, ushort_t* __restrict__ W2Th,
                         ushort_t* __restrict__ W2Tl) {
    int tid = blockIdx.x * 256 + threadIdx.x;
    if (tid >= 128 * 384) return;
    int c = tid / 384;
    int hk = tid - c * 384;
    int h = hk >> 7, k = hk & 127;
    float v = (k < FIN) ? W2[(h * FIN + k) * D2 + c] : 0.f;
    ushort_t hi, lo;
    split2(v, hi, lo);
    W2Th[tid] = hi;
    W2Tl[tid] = lo;
}

// ===== xP[n][128] = x[n][0..113], pad 0 =====
__global__ void k_xp(const float* __restrict__ x, float* __restrict__ xP) {
    int tid = blockIdx.x * 256 + threadIdx.x;
    if (tid >= NN * 128) return;
    int n = tid >> 7, c = tid & 127;
    xP[tid] = (c < FIN) ? x[n * FIN + c] : 0.f;
}

// ===== as1/ad1 = x @ was/wad =====
__global__ __launch_bounds__(256) void k_alpha1x(const float* __restrict__ x,
                                                 const float* __restrict__ was,
                                                 const float* __restrict__ wad,
                                                 float* __restrict__ as1,
                                                 float* __restrict__ ad1) {
    int n = blockIdx.x * 4 + (threadIdx.x >> 6);
    int l = threadIdx.x & 63;
    if (n >= NN) return;
    float x0 = x[n * FIN + l];
    float x1 = (l < FIN - 64) ? x[n * FIN + 64 + l] : 0.f;
    float s[H1], d[H1];
#pragma unroll
    for (int h = 0; h < H1; h++) {
        float w0s = was[l * H1 + h], w0d = wad[l * H1 + h];
        float w1s = (l < FIN - 64) ? was[(64 + l) * H1 + h] : 0.f;
        float w1d = (l < FIN - 64) ? wad[(64 + l) * H1 + h] : 0.f;
        s[h] = x0 * w0s + x1 * w1s;
        d[h] = x0 * w0d + x1 * w1d;
    }
#pragma unroll
    for (int o = 32; o > 0; o >>= 1) {
#pragma unroll
        for (int h = 0; h < H1; h++) {
            s[h] += __shfl_down(s[h], o);
            d[h] += __shfl_down(d[h], o);
        }
    }
    if (l == 0) {
#pragma unroll
        for (int h = 0; h < H1; h++) {
            as1[n * H1 + h] = s[h];
            ad1[n * H1 + h] = d[h];
        }
    }
}

// ===================== CSR build =====================
__global__ void k_count(const int* __restrict__ dst, int* __restrict__ cnt) {
    int e = blockIdx.x * 256 + threadIdx.x;
    if (e < EE) atomicAdd(&cnt[dst[e]], 1);
}

__global__ __launch_bounds__(1024) void k_scan(const int* __restrict__ cnt,
                                               int* __restrict__ off) {
    __shared__ int part[1024];
    int t = threadIdx.x;
    const int CH = 20;
    int loc[CH];
    int s = 0;
    int base = t * CH;
    for (int i = 0; i < CH; i++) {
        int idx = base + i;
        int v = (idx < NN) ? cnt[idx] : 0;
        loc[i] = s;
        s += v;
    }
    part[t] = s;
    __syncthreads();
    for (int d = 1; d < 1024; d <<= 1) {
        int v = (t >= d) ? part[t - d] : 0;
        __syncthreads();
        part[t] += v;
        __syncthreads();
    }
    int pre = (t == 0) ? 0 : part[t - 1];
    for (int i = 0; i < CH; i++) {
        int idx = base + i;
        if (idx < NN) off[idx] = pre + loc[i];
    }
    if (t == 1023) off[NN] = part[1023];
}

__global__ void k_scatter(const int* __restrict__ src, const int* __restrict__ dst,
                          const int* __restrict__ off, int* __restrict__ cur,
                          int* __restrict__ csr_src) {
    int e = blockIdx.x * 256 + threadIdx.x;
    if (e < EE) {
        int d = dst[e];
        int pos = off[d] + atomicAdd(&cur[d], 1);
        csr_src[pos] = src[e];
    }
}

// ===== layer-1 gather: float4/lane, 4 edge-groups x 32 lanes =====
// Per block (node n): stage 64 edges; group g handles edges j=g,g+4,...
// lane covers cols c32*4..+3 via one float4 load per edge (512B/row/wave-instr).
__global__ __launch_bounds__(128) void k_aggx(const float* __restrict__ xP,
                                              const float* __restrict__ as1,
                                              const float* __restrict__ ad1,
                                              const int* __restrict__ off,
                                              const int* __restrict__ csr_src,
                                              ushort_t* __restrict__ xgh,
                                              ushort_t* __restrict__ xgl) {
    int n = blockIdx.x, t = threadIdx.x;
    int g = t >> 5, c32 = t & 31;
    int col0 = c32 * 4;
    int e0 = off[n], e1 = off[n + 1];
    float adv0 = ad1[n * H1 + 0], adv1 = ad1[n * H1 + 1], adv2 = ad1[n * H1 + 2];
    __shared__ int ssrc[64];
    __shared__ float sw[64][H1];
    __shared__ f32x4 red[4][32][H1];
    __shared__ float sums[H1];
    f32x4 a0 = {0, 0, 0, 0}, a1 = {0, 0, 0, 0}, a2 = {0, 0, 0, 0};
    float ps0 = 0.f, ps1 = 0.f, ps2 = 0.f;
    for (int base = e0; base < e1; base += 64) {
        int c = min(64, e1 - base);
        __syncthreads();
        if (t < c) {
            int s = csr_src[base + t];
            ssrc[t] = s;
            float w0 = __expf(lrelu(as1[s * H1 + 0] + adv0));
            float w1 = __expf(lrelu(as1[s * H1 + 1] + adv1));
            float w2 = __expf(lrelu(as1[s * H1 + 2] + adv2));
            sw[t][0] = w0; sw[t][1] = w1; sw[t][2] = w2;
            ps0 += w0; ps1 += w1; ps2 += w2;
        }
        __syncthreads();
        for (int j = g; j < c; j += 4) {
            int s = ssrc[j];
            f32x4 v = *(const f32x4*)(xP + (size_t)s * 128 + col0);
            float w0 = sw[j][0], w1 = sw[j][1], w2 = sw[j][2];
            a0 += v * w0;
            a1 += v * w1;
            a2 += v * w2;
        }
    }
    // weight sums: staging lanes are wave 0 only
    if (t < 64) {
#pragma unroll
        for (int o = 32; o > 0; o >>= 1) {
            ps0 += __shfl_down(ps0, o);
            ps1 += __shfl_down(ps1, o);
            ps2 += __shfl_down(ps2, o);
        }
        if (t == 0) { sums[0] = ps0; sums[1] = ps1; sums[2] = ps2; }
    }
    red[g][c32][0] = a0;
    red[g][c32][1] = a1;
    red[g][c32][2] = a2;
    __syncthreads();
    if (t < 32) {
        f32x4 r0 = red[0][t][0] + red[1][t][0] + red[2][t][0] + red[3][t][0];
        f32x4 r1 = red[0][t][1] + red[1][t][1] + red[2][t][1] + red[3][t][1];
        f32x4 r2 = red[0][t][2] + red[1][t][2] + red[2][t][2] + red[3][t][2];
        float i0 = 1.f / sums[0], i1 = 1.f / sums[1], i2 = 1.f / sums[2];
        int cb = t * 4;
        ushort4v h4, l4;
#pragma unroll
        for (int q = 0; q < 4; q++) { ushort_t hh, ll; split2(r0[q] * i0, hh, ll); h4[q] = hh; l4[q] = ll; }
        *(ushort4v*)(xgh + (size_t)0 * NN * 128 + (size_t)n * 128 + cb) = h4;
        *(ushort4v*)(xgl + (size_t)0 * NN * 128 + (size_t)n * 128 + cb) = l4;
#pragma unroll
        for (int q = 0; q < 4; q++) { ushort_t hh, ll; split2(r1[q] * i1, hh, ll); h4[q] = hh; l4[q] = ll; }
        *(ushort4v*)(xgh + (size_t)1 * NN * 128 + (size_t)n * 128 + cb) = h4;
        *(ushort4v*)(xgl + (size_t)1 * NN * 128 + (size_t)n * 128 + cb) = l4;
#pragma unroll
        for (int q = 0; q < 4; q++) { ushort_t hh, ll; split2(r2[q] * i2, hh, ll); h4[q] = hh; l4[q] = ll; }
        *(ushort4v*)(xgh + (size_t)2 * NN * 128 + (size_t)n * 128 + cb) = h4;
        *(ushort4v*)(xgl + (size_t)2 * NN * 128 + (size_t)n * 128 + cb) = l4;
    }
}

// ===== layer-2 gather: float4/lane + relu + pool atomicMax =====
__global__ __launch_bounds__(128) void k_agg2f(const float* __restrict__ h2,
                                               const float* __restrict__ as2,
                                               const float* __restrict__ ad2,
                                               const int* __restrict__ off,
                                               const int* __restrict__ csr_src,
                                               const float* __restrict__ b2,
                                               unsigned* __restrict__ poolbuf) {
    int n = blockIdx.x, t = threadIdx.x;
    int g = t >> 5, c32 = t & 31;
    int col0 = c32 * 4;
    int e0 = off[n], e1 = off[n + 1];
    float adv = ad2[n];
    __shared__ int ssrc[64];
    __shared__ float sw[64];
    __shared__ f32x4 red[4][32];
    __shared__ float ssum;
    f32x4 acc = {0, 0, 0, 0};
    float ps = 0.f;
    for (int base = e0; base < e1; base += 64) {
        int c = min(64, e1 - base);
        __syncthreads();
        if (t < c) {
            int s = csr_src[base + t];
            ssrc[t] = s;
            float w = __expf(lrelu(as2[s] + adv));
            sw[t] = w;
            ps += w;
        }
        __syncthreads();
        for (int j = g; j < c; j += 4) {
            f32x4 v = *(const f32x4*)(h2 + (size_t)ssrc[j] * D2 + col0);
            acc += v * sw[j];
        }
    }
    if (t < 64) {
#pragma unroll
        for (int o = 32; o > 0; o >>= 1) ps += __shfl_down(ps, o);
        if (t == 0) ssum = ps;
    }
    red[g][c32] = acc;
    __syncthreads();
    if (t < 32) {
        f32x4 r = red[0][t] + red[1][t] + red[2][t] + red[3][t];
        float inv = 1.f / ssum;
        int gidx = (int)(((long long)n * GG) / NN);   // batch[n] = n*G//N
        int cb = t * 4;
#pragma unroll
        for (int q = 0; q < 4; q++) {
            float v = fmaxf(r[q] * inv + b2[cb + q], 0.f);
            atomicMax(&poolbuf[gidx * D2 + cb + q], fenc(v));
        }
    }
}

// ===== GEMM1 (MFMA bf16x3, B staged in LDS): h1 = ELU(xagg_h @ W1_h + b1) =====
__global__ __launch_bounds__(256) void k_gemm1m(const ushort_t* __restrict__ xgh,
                                                const ushort_t* __restrict__ xgl,
                                                const ushort_t* __restrict__ W1Th,
                                                const ushort_t* __restrict__ W1Tl,
                                                const float* __restrict__ b1,
                                                ushort_t* __restrict__ h1hi,
                                                ushort_t* __restrict__ h1lo) {
    int h = blockIdx.y;
    int rb = blockIdx.x * 128;
    int tid = threadIdx.x;
    int w = tid >> 6, l = tid & 63;
    int m = l & 15, g = l >> 4;
    int r0 = rb + w * 32 + m;
    int r1 = r0 + 16;
    bool ok0 = (r0 < NN), ok1 = (r1 < NN);
    const ushort_t* xh = xgh + (size_t)h * NN * 128;
    const ushort_t* xl = xgl + (size_t)h * NN * 128;
    const ushort_t* Bhg = W1Th + (size_t)h * 128 * 128;
    const ushort_t* Blg = W1Tl + (size_t)h * 128 * 128;
    const short8v z8 = {0, 0, 0, 0, 0, 0, 0, 0};
    __shared__ __align__(16) ushort_t BsH[128 * 40];   // row stride 40 hw = 80B
    __shared__ __align__(16) ushort_t BsL[128 * 40];
    f32x4 acc0[8], acc1[8];
#pragma unroll
    for (int j = 0; j < 8; j++) {
        acc0[j] = (f32x4){0.f, 0.f, 0.f, 0.f};
        acc1[j] = (f32x4){0.f, 0.f, 0.f, 0.f};
    }
    for (int k0i = 0; k0i < 4; k0i++) {
        int k0 = k0i * 32;
        __syncthreads();
        int ka = k0 + g * 8;
        short8v a0h = ok0 ? *(const short8v*)(xh + (size_t)r0 * 128 + ka) : z8;
        short8v a0l = ok0 ? *(const short8v*)(xl + (size_t)r0 * 128 + ka) : z8;
        short8v a1h = ok1 ? *(const short8v*)(xh + (size_t)r1 * 128 + ka) : z8;
        short8v a1l = ok1 ? *(const short8v*)(xl + (size_t)r1 * 128 + ka) : z8;
#pragma unroll
        for (int it = 0; it < 2; it++) {
            int idx = tid + it * 256;
            int c = idx >> 2, q = idx & 3;
            size_t go = (size_t)c * 128 + k0 + q * 8;
            int lo_off = c * 40 + q * 8;
            *(short8v*)(&BsH[lo_off]) = *(const short8v*)(Bhg + go);
            *(short8v*)(&BsL[lo_off]) = *(const short8v*)(Blg + go);
        }
        __syncthreads();
#pragma unroll
        for (int j = 0; j < 8; j++) {
            int c = j * 16 + m;
            short8v bh = *(const short8v*)(&BsH[c * 40 + g * 8]);
            short8v bl = *(const short8v*)(&BsL[c * 40 + g * 8]);
            acc0[j] = __builtin_amdgcn_mfma_f32_16x16x32_bf16(a0h, bh, acc0[j], 0, 0, 0);
            acc1[j] = __builtin_amdgcn_mfma_f32_16x16x32_bf16(a1h, bh, acc1[j], 0, 0, 0);
            acc0[j] = __builtin_amdgcn_mfma_f32_16x16x32_bf16(a0h, bl, acc0[j], 0, 0, 0);
            acc1[j] = __builtin_amdgcn_mfma_f32_16x16x32_bf16(a1h, bl, acc1[j], 0, 0, 0);
            acc0[j] = __builtin_amdgcn_mfma_f32_16x16x32_bf16(a0l, bh, acc0[j], 0, 0, 0);
            acc1[j] = __builtin_amdgcn_mfma_f32_16x16x32_bf16(a1l, bh, acc1[j], 0, 0, 0);
        }
    }
    ushort_t* Hh = h1hi + (size_t)h * NN * 128;
    ushort_t* Hl = h1lo + (size_t)h * NN * 128;
#pragma unroll
    for (int j = 0; j < 8; j++) {
        int c = j * 16 + m;
        float bv = (c < FIN) ? b1[h * FIN + c] : 0.f;
#pragma unroll
        for (int r = 0; r < 4; r++) {
            int orow0 = rb + w * 32 + g * 4 + r;
            int orow1 = orow0 + 16;
            if (orow0 < NN) {
                float v = acc0[j][r] + bv;
                v = v > 0.f ? v : expm1f(v);
                ushort_t hi = 0, lo = 0;
                if (c < FIN) split2(v, hi, lo);
                Hh[(size_t)orow0 * 128 + c] = hi;
                Hl[(size_t)orow0 * 128 + c] = lo;
            }
            if (orow1 < NN) {
                float v = acc1[j][r] + bv;
                v = v > 0.f ? v : expm1f(v);
                ushort_t hi = 0, lo = 0;
                if (c < FIN) split2(v, hi, lo);
                Hh[(size_t)orow1 * 128 + c] = hi;
                Hl[(size_t)orow1 * 128 + c] = lo;
            }
        }
    }
}

// ===== GEMM2 (MFMA bf16x3, B staged in LDS, fused alpha2): h2 = h1 @ W2 =====
__global__ __launch_bounds__(256) void k_gemm2m(const ushort_t* __restrict__ h1hi,
                                                const ushort_t* __restrict__ h1lo,
                                                const ushort_t* __restrict__ W2Th,
                                                const ushort_t* __restrict__ W2Tl,
                                                const float* __restrict__ aS2,
                                                const float* __restrict__ aD2,
                                                float* __restrict__ h2,
                                                float* __restrict__ as2,
                                                float* __restrict__ ad2) {
    int rb = blockIdx.x * 128;
    int tid = threadIdx.x;
    int w = tid >> 6, l = tid & 63;
    int m = l & 15, g = l >> 4;
    int r0 = rb + w * 32 + m;
    int r1 = r0 + 16;
    bool ok0 = (r0 < NN), ok1 = (r1 < NN);
    const short8v z8 = {0, 0, 0, 0, 0, 0, 0, 0};
    __shared__ __align__(16) ushort_t BsH[128 * 40];
    __shared__ __align__(16) ushort_t BsL[128 * 40];
    f32x4 acc0[8], acc1[8];
#pragma unroll
    for (int j = 0; j < 8; j++) {
        acc0[j] = (f32x4){0.f, 0.f, 0.f, 0.f};
        acc1[j] = (f32x4){0.f, 0.f, 0.f, 0.f};
    }
    for (int k0i = 0; k0i < 12; k0i++) {
        int k0 = k0i * 32;
        __syncthreads();
        int hh = k0 >> 7;
        int kc = (k0 & 127) + g * 8;
        size_t a0o = ((size_t)hh * NN + (size_t)(ok0 ? r0 : 0)) * 128 + kc;
        size_t a1o = ((size_t)hh * NN + (size_t)(ok1 ? r1 : 0)) * 128 + kc;
        short8v a0h = ok0 ? *(const short8v*)(h1hi + a0o) : z8;
        short8v a0l = ok0 ? *(const short8v*)(h1lo + a0o) : z8;
        short8v a1h = ok1 ? *(const short8v*)(h1hi + a1o) : z8;
        short8v a1l = ok1 ? *(const short8v*)(h1lo + a1o) : z8;
#pragma unroll
        for (int it = 0; it < 2; it++) {
            int idx = tid + it * 256;
            int c = idx >> 2, q = idx & 3;
            size_t go = (size_t)c * 384 + k0 + q * 8;
            int lo_off = c * 40 + q * 8;
            *(short8v*)(&BsH[lo_off]) = *(const short8v*)(W2Th + go);
            *(short8v*)(&BsL[lo_off]) = *(const short8v*)(W2Tl + go);
        }
        __syncthreads();
#pragma unroll
        for (int j = 0; j < 8; j++) {
            int c = j * 16 + m;
            short8v bh = *(const short8v*)(&BsH[c * 40 + g * 8]);
            short8v bl = *(const short8v*)(&BsL[c * 40 + g * 8]);
            acc0[j] = __builtin_amdgcn_mfma_f32_16x16x32_bf16(a0h, bh, acc0[j], 0, 0, 0);
            acc1[j] = __builtin_amdgcn_mfma_f32_16x16x32_bf16(a1h, bh, acc1[j], 0, 0, 0);
            acc0[j] = __builtin_amdgcn_mfma_f32_16x16x32_bf16(a0h, bl, acc0[j], 0, 0, 0);
            acc1[j] = __builtin_amdgcn_mfma_f32_16x16x32_bf16(a1h, bl, acc1[j], 0, 0, 0);
            acc0[j] = __builtin_amdgcn_mfma_f32_16x16x32_bf16(a0l, bh, acc0[j], 0, 0, 0);
            acc1[j] = __builtin_amdgcn_mfma_f32_16x16x32_bf16(a1l, bh, acc1[j], 0, 0, 0);
        }
    }
#pragma unroll
    for (int j = 0; j < 8; j++) {
        int c = j * 16 + m;
#pragma unroll
        for (int r = 0; r < 4; r++) {
            int orow0 = rb + w * 32 + g * 4 + r;
            int orow1 = orow0 + 16;
            if (orow0 < NN) h2[(size_t)orow0 * D2 + c] = acc0[j][r];
            if (orow1 < NN) h2[(size_t)orow1 * D2 + c] = acc1[j][r];
        }
    }
    // fused alpha2: per output row, dot with aS2/aD2 over 128 cols.
    // Row (g,r): lanes l = g*16 + m (m=0..15) hold cols j*16+m.
    float sv[8], dv[8];
#pragma unroll
    for (int j = 0; j < 8; j++) {
        sv[j] = aS2[j * 16 + m];
        dv[j] = aD2[j * 16 + m];
    }
#pragma unroll
    for (int r = 0; r < 4; r++) {
        float s0 = 0.f, d0 = 0.f, s1 = 0.f, d1 = 0.f;
#pragma unroll
        for (int j = 0; j < 8; j++) {
            s0 += acc0[j][r] * sv[j];
            d0 += acc0[j][r] * dv[j];
            s1 += acc1[j][r] * sv[j];
            d1 += acc1[j][r] * dv[j];
        }
#pragma unroll
        for (int o = 1; o < 16; o <<= 1) {
            s0 += __shfl_xor(s0, o);
            d0 += __shfl_xor(d0, o);
            s1 += __shfl_xor(s1, o);
            d1 += __shfl_xor(d1, o);
        }
        int orow0 = rb + w * 32 + g * 4 + r;
        int orow1 = orow0 + 16;
        if (m == 0) {
            if (orow0 < NN) { as2[orow0] = s0; ad2[orow0] = d0; }
            if (orow1 < NN) { as2[orow1] = s1; ad2[orow1] = d1; }
        }
    }
}

// ===== MLP head =====
__global__ __launch_bounds__(128) void k_mlp(const unsigned* __restrict__ poolbuf,
                                             const float* __restrict__ Wg,
                                             const float* __restrict__ bg,
                                             const float* __restrict__ Wf1,
                                             const float* __restrict__ bf1,
                                             const float* __restrict__ Wf2,
                                             const float* __restrict__ bf2,
                                             const float* __restrict__ Wo,
                                             const float* __restrict__ bo,
                                             float* __restrict__ out) {
    int g = blockIdx.x;
    int t = threadIdx.x;
    __shared__ float pool[D2];
    __shared__ float a1[64];
    __shared__ float a2[32];
    __shared__ float a3[16];
    pool[t] = fdec(poolbuf[g * D2 + t]);
    __syncthreads();
    if (t < 64) {
        float acc = bg[t];
        for (int k = 0; k < D2; k++) acc += pool[k] * Wg[k * 64 + t];
        a1[t] = fmaxf(acc, 0.f);
    }
    __syncthreads();
    if (t < 32) {
        float acc = bf1[t];
        for (int k = 0; k < 64; k++) acc += a1[k] * Wf1[k * 32 + t];
        a2[t] = fmaxf(acc, 0.f);
    }
    __syncthreads();
    if (t < 16) {
        float acc = bf2[t];
        for (int k = 0; k < 32; k++) acc += a2[k] * Wf2[k * 16 + t];
        a3[t] = fmaxf(acc, 0.f);
    }
    __syncthreads();
    if (t == 0) {
        float acc = bo[0];
        for (int k = 0; k < 16; k++) acc += a3[k] * Wo[k];
        out[g] = acc;
    }
}

extern "C" void kernel_launch(void* const* d_in, const int* in_sizes, int n_in,
                              void* d_out, int out_size, void* d_ws, size_t ws_size,
                              hipStream_t stream) {
    const float* x = (const float*)d_in[0];
    const int* ei = (const int*)d_in[1];
    const float* W1 = (const float*)d_in[3];
    const float* aS1 = (const float*)d_in[4];
    const float* aD1 = (const float*)d_in[5];
    const float* b1 = (const float*)d_in[6];
    const float* W2 = (const float*)d_in[7];
    const float* aS2 = (const float*)d_in[8];
    const float* aD2 = (const float*)d_in[9];
    const float* b2 = (const float*)d_in[10];
    const float* Wg = (const float*)d_in[11];
    const float* bg = (const float*)d_in[12];
    const float* Wf1 = (const float*)d_in[13];
    const float* bf1 = (const float*)d_in[14];
    const float* Wf2 = (const float*)d_in[15];
    const float* bf2 = (const float*)d_in[16];
    const float* Wo = (const float*)d_in[17];
    const float* bo = (const float*)d_in[18];
    float* out = (float*)d_out;

    const int* src = ei;
    const int* dst = ei + EE;

    char* ws = (char*)d_ws;
    size_t o = 0;
    auto alloc = [&](size_t bytes) -> char* {
        char* p = ws + o;
        o += (bytes + 255) & ~(size_t)255;
        return p;
    };
    float* was = (float*)alloc((size_t)FIN * H1 * 4);
    float* wad = (float*)alloc((size_t)FIN * H1 * 4);
    ushort_t* W1Th = (ushort_t*)alloc((size_t)H1 * 128 * 128 * 2);
    ushort_t* W1Tl = (ushort_t*)alloc((size_t)H1 * 128 * 128 * 2);
    ushort_t* W2Th = (ushort_t*)alloc((size_t)128 * 384 * 2);
    ushort_t* W2Tl = (ushort_t*)alloc((size_t)128 * 384 * 2);
    float* xP = (float*)alloc((size_t)NN * 128 * 4);
    float* as1 = (float*)alloc((size_t)NN * H1 * 4);
    float* ad1 = (float*)alloc((size_t)NN * H1 * 4);
    int* cnt = (int*)alloc((size_t)NN * 4);
    int* off = (int*)alloc((size_t)(NN + 1) * 4);
    int* cur = (int*)alloc((size_t)NN * 4);
    int* csr_src = (int*)alloc((size_t)EE * 4);
    ushort_t* xgh = (ushort_t*)alloc((size_t)H1 * NN * 128 * 2);
    ushort_t* xgl = (ushort_t*)alloc((size_t)H1 * NN * 128 * 2);
    ushort_t* h1hi = (ushort_t*)alloc((size_t)H1 * NN * 128 * 2);
    ushort_t* h1lo = (ushort_t*)alloc((size_t)H1 * NN * 128 * 2);
    float* h2 = (float*)alloc((size_t)NN * D2 * 4);
    float* as2 = (float*)alloc((size_t)NN * 4);
    float* ad2 = (float*)alloc((size_t)NN * 4);
    unsigned* poolbuf = (unsigned*)alloc((size_t)GG * D2 * 4);
    (void)ws_size;

    hipMemsetAsync(cnt, 0, (size_t)NN * 4, stream);
    hipMemsetAsync(cur, 0, (size_t)NN * 4, stream);
    hipMemsetAsync(poolbuf, 0, (size_t)GG * D2 * 4, stream);

    const int EB = (EE + 255) / 256;

    k_wa<<<(2 * FIN * H1 + 255) / 256, 256, 0, stream>>>(W1, aS1, aD1, was, wad);
    k_prep1m<<<(H1 * 128 * 128 + 255) / 256, 256, 0, stream>>>(W1, W1Th, W1Tl);
    k_prep2m<<<(128 * 384 + 255) / 256, 256, 0, stream>>>(W2, W2Th, W2Tl);
    k_xp<<<(NN * 128 + 255) / 256, 256, 0, stream>>>(x, xP);
    k_alpha1x<<<(NN + 3) / 4, 256, 0, stream>>>(x, was, wad, as1, ad1);
    k_count<<<EB, 256, 0, stream>>>(dst, cnt);
    k_scan<<<1, 1024, 0, stream>>>(cnt, off);
    k_scatter<<<EB, 256, 0, stream>>>(src, dst, off, cur, csr_src);
    k_aggx<<<NN, 128, 0, stream>>>(xP, as1, ad1, off, csr_src, xgh, xgl);
    k_gemm1m<<<dim3((NN + 127) / 128, H1), 256, 0, stream>>>(xgh, xgl, W1Th, W1Tl, b1, h1hi, h1lo);
    k_gemm2m<<<(NN + 127) / 128, 256, 0, stream>>>(h1hi, h1lo, W2Th, W2Tl, aS2, aD2, h2, as2, ad2);
    k_agg2f<<<NN, 128, 0, stream>>>(h2, as2, ad2, off, csr_src, b2, poolbuf);
    k_mlp<<<GG, 128, 0, stream>>>(poolbuf, Wg, bg, Wf1, bf1, Wf2, bf2, Wo, bo, out);
}

// Round 17
// 289.639 us; speedup vs baseline: 1.1204x; 1.1204x over previous
//
#include <hip/hip_runtime.h>

#define NN 20000
#define EE 660000      // 640000 + 20000 self loops
#define GG 64
#define FIN 114
#define H1 3
#define F1 342         // H1*FIN
#define D2 128
#define NEG 0.2f

typedef __attribute__((ext_vector_type(8))) short short8v;
typedef __attribute__((ext_vector_type(4))) float f32x4;
typedef unsigned short ushort_t;

__device__ inline unsigned fenc(float f) {
    unsigned u = __float_as_uint(f);
    return (u & 0x80000000u) ? ~u : (u | 0x80000000u);
}
__device__ inline float fdec(unsigned u) {
    return (u & 0x80000000u) ? __uint_as_float(u & 0x7FFFFFFFu) : __uint_as_float(~u);
}
__device__ inline float lrelu(float x) { return x > 0.f ? x : NEG * x; }

// fp32 -> bf16 hi (truncate) + bf16 lo (RNE of residual); x ≈ hi + lo to ~2^-17
__device__ inline void split2(float x, ushort_t& hi, ushort_t& lo) {
    unsigned u = __float_as_uint(x);
    unsigned uh = u & 0xFFFF0000u;
    hi = (ushort_t)(uh >> 16);
    float r = x - __uint_as_float(uh);
    unsigned v = __float_as_uint(r);
    unsigned vh = (v + 0x7FFFu + ((v >> 16) & 1u)) & 0xFFFF0000u;
    lo = (ushort_t)(vh >> 16);
}

// ===== fold a_src/a_dst through W1 =====
__global__ void k_wa(const float* __restrict__ W1, const float* __restrict__ aS,
                     const float* __restrict__ aD, float* __restrict__ was,
                     float* __restrict__ wad) {
    int tid = blockIdx.x * 256 + threadIdx.x;
    if (tid >= 2 * FIN * H1) return;
    int which = tid >= FIN * H1;
    int i = which ? tid - FIN * H1 : tid;
    int k = i / H1, h = i % H1;
    const float* a = which ? aD : aS;
    float s = 0.f;
    for (int d = 0; d < FIN; d++) s += W1[k * F1 + h * FIN + d] * a[h * FIN + d];
    (which ? wad : was)[i] = s;
}

// ===== W1 prep: W1T[h][c][k] hi/lo bf16, c,k in [0,128) zero-padded =====
__global__ void k_prep1m(const float* __restrict__ W1, ushort_t* __restrict__ W1Th,
                         ushort_t* __restrict__ W1Tl) {
    int tid = blockIdx.x * 256 + threadIdx.x;
    if (tid >= H1 * 128 * 128) return;
    int h = tid / (128 * 128);
    int rem = tid & (128 * 128 - 1);
    int c = rem >> 7, k = rem & 127;
    float v = (c < FIN && k < FIN) ? W1[k * F1 + h * FIN + c] : 0.f;
    ushort_t hi, lo;
    split2(v, hi, lo);
    W1Th[tid] = hi;
    W1Tl[tid] = lo;
}

// ===== W2 prep: W2T[c][hk] hi/lo bf16, hk = h*128+k (k zero-padded) =====
__global__ void k_prep2m(const float* __restrict__ W2, ushort_t* __restrict__ W2Th,
                         ushort_t* __restrict__ W2Tl) {
    int tid = blockIdx.x * 256 + threadIdx.x;
    if (tid >= 128 * 384) return;
    int c = tid / 384;
    int hk = tid - c * 384;
    int h = hk >> 7, k = hk & 127;
    float v = (k < FIN) ? W2[(h * FIN + k) * D2 + c] : 0.f;
    ushort_t hi, lo;
    split2(v, hi, lo);
    W2Th[tid] = hi;
    W2Tl[tid] = lo;
}

// ===== as1/ad1 = x @ was/wad =====
__global__ __launch_bounds__(256) void k_alpha1x(const float* __restrict__ x,
                                                 const float* __restrict__ was,
                                                 const float* __restrict__ wad,
                                                 float* __restrict__ as1,
                                                 float* __restrict__ ad1) {
    int n = blockIdx.x * 4 + (threadIdx.x >> 6);
    int l = threadIdx.x & 63;
    if (n >= NN) return;
    float x0 = x[n * FIN + l];
    float x1 = (l < FIN - 64) ? x[n * FIN + 64 + l] : 0.f;
    float s[H1], d[H1];
#pragma unroll
    for (int h = 0; h < H1; h++) {
        float w0s = was[l * H1 + h], w0d = wad[l * H1 + h];
        float w1s = (l < FIN - 64) ? was[(64 + l) * H1 + h] : 0.f;
        float w1d = (l < FIN - 64) ? wad[(64 + l) * H1 + h] : 0.f;
        s[h] = x0 * w0s + x1 * w1s;
        d[h] = x0 * w0d + x1 * w1d;
    }
#pragma unroll
    for (int o = 32; o > 0; o >>= 1) {
#pragma unroll
        for (int h = 0; h < H1; h++) {
            s[h] += __shfl_down(s[h], o);
            d[h] += __shfl_down(d[h], o);
        }
    }
    if (l == 0) {
#pragma unroll
        for (int h = 0; h < H1; h++) {
            as1[n * H1 + h] = s[h];
            ad1[n * H1 + h] = d[h];
        }
    }
}

// ===================== CSR build =====================
__global__ void k_count(const int* __restrict__ dst, int* __restrict__ cnt) {
    int e = blockIdx.x * 256 + threadIdx.x;
    if (e < EE) atomicAdd(&cnt[dst[e]], 1);
}

__global__ __launch_bounds__(1024) void k_scan(const int* __restrict__ cnt,
                                               int* __restrict__ off) {
    __shared__ int part[1024];
    int t = threadIdx.x;
    const int CH = 20;
    int loc[CH];
    int s = 0;
    int base = t * CH;
    for (int i = 0; i < CH; i++) {
        int idx = base + i;
        int v = (idx < NN) ? cnt[idx] : 0;
        loc[i] = s;
        s += v;
    }
    part[t] = s;
    __syncthreads();
    for (int d = 1; d < 1024; d <<= 1) {
        int v = (t >= d) ? part[t - d] : 0;
        __syncthreads();
        part[t] += v;
        __syncthreads();
    }
    int pre = (t == 0) ? 0 : part[t - 1];
    for (int i = 0; i < CH; i++) {
        int idx = base + i;
        if (idx < NN) off[idx] = pre + loc[i];
    }
    if (t == 1023) off[NN] = part[1023];
}

__global__ void k_scatter(const int* __restrict__ src, const int* __restrict__ dst,
                          const int* __restrict__ off, int* __restrict__ cur,
                          int* __restrict__ csr_src) {
    int e = blockIdx.x * 256 + threadIdx.x;
    if (e < EE) {
        int d = dst[e];
        int pos = off[d] + atomicAdd(&cur[d], 1);
        csr_src[pos] = src[e];
    }
}

// ===== layer-1: fused softmax+aggregate of x -> xg hi/lo bf16 [3][N][128] =====
// (r15 structure: scalar coalesced loads, 64-edge staging, 4-deep unroll)
__global__ __launch_bounds__(128) void k_aggx(const float* __restrict__ x,
                                              const float* __restrict__ as1,
                                              const float* __restrict__ ad1,
                                              const int* __restrict__ off,
                                              const int* __restrict__ csr_src,
                                              ushort_t* __restrict__ xgh,
                                              ushort_t* __restrict__ xgl) {
    int n = blockIdx.x, t = threadIdx.x;
    int e0 = off[n], e1 = off[n + 1];
    float adv0 = ad1[n * H1 + 0], adv1 = ad1[n * H1 + 1], adv2 = ad1[n * H1 + 2];
    __shared__ int ssrc[64];
    __shared__ float sw[64][H1];
    __shared__ float red[64][H1];
    float acc0 = 0.f, acc1 = 0.f, acc2 = 0.f;
    float ps0 = 0.f, ps1 = 0.f, ps2 = 0.f;
    for (int base = e0; base < e1; base += 64) {
        int c = min(64, e1 - base);
        __syncthreads();
        if (t < c) {
            int s = csr_src[base + t];
            ssrc[t] = s;
            float w0 = __expf(lrelu(as1[s * H1 + 0] + adv0));
            float w1 = __expf(lrelu(as1[s * H1 + 1] + adv1));
            float w2 = __expf(lrelu(as1[s * H1 + 2] + adv2));
            sw[t][0] = w0; sw[t][1] = w1; sw[t][2] = w2;
            ps0 += w0; ps1 += w1; ps2 += w2;
        }
        __syncthreads();
        if (t < FIN) {
            int j = 0;
            for (; j + 4 <= c; j += 4) {
                int s0 = ssrc[j + 0], s1 = ssrc[j + 1];
                int s2 = ssrc[j + 2], s3 = ssrc[j + 3];
                float v0 = x[(size_t)s0 * FIN + t];
                float v1 = x[(size_t)s1 * FIN + t];
                float v2 = x[(size_t)s2 * FIN + t];
                float v3 = x[(size_t)s3 * FIN + t];
                acc0 += v0 * sw[j + 0][0]; acc1 += v0 * sw[j + 0][1]; acc2 += v0 * sw[j + 0][2];
                acc0 += v1 * sw[j + 1][0]; acc1 += v1 * sw[j + 1][1]; acc2 += v1 * sw[j + 1][2];
                acc0 += v2 * sw[j + 2][0]; acc1 += v2 * sw[j + 2][1]; acc2 += v2 * sw[j + 2][2];
                acc0 += v3 * sw[j + 3][0]; acc1 += v3 * sw[j + 3][1]; acc2 += v3 * sw[j + 3][2];
            }
            for (; j < c; j++) {
                float xv = x[(size_t)ssrc[j] * FIN + t];
                acc0 += xv * sw[j][0];
                acc1 += xv * sw[j][1];
                acc2 += xv * sw[j][2];
            }
        }
    }
    __syncthreads();
    if (t < 64) { red[t][0] = ps0; red[t][1] = ps1; red[t][2] = ps2; }
    __syncthreads();
    for (int sr = 32; sr > 0; sr >>= 1) {
        if (t < sr) {
            red[t][0] += red[t + sr][0];
            red[t][1] += red[t + sr][1];
            red[t][2] += red[t + sr][2];
        }
        __syncthreads();
    }
    float i0 = 1.f / red[0][0], i1 = 1.f / red[0][1], i2 = 1.f / red[0][2];
    float v0 = (t < FIN) ? acc0 * i0 : 0.f;
    float v1 = (t < FIN) ? acc1 * i1 : 0.f;
    float v2 = (t < FIN) ? acc2 * i2 : 0.f;
    ushort_t hi, lo;
    split2(v0, hi, lo);
    xgh[(size_t)0 * NN * 128 + n * 128 + t] = hi;
    xgl[(size_t)0 * NN * 128 + n * 128 + t] = lo;
    split2(v1, hi, lo);
    xgh[(size_t)1 * NN * 128 + n * 128 + t] = hi;
    xgl[(size_t)1 * NN * 128 + n * 128 + t] = lo;
    split2(v2, hi, lo);
    xgh[(size_t)2 * NN * 128 + n * 128 + t] = hi;
    xgl[(size_t)2 * NN * 128 + n * 128 + t] = lo;
}

// ===== layer-2: fused softmax+aggregate+relu+POOL =====
// wave-parity edge split: wave w handles j%2==w; lane covers 2 cols (float2);
// each wave-instruction reads one contiguous 512B row.
__global__ __launch_bounds__(128) void k_agg2f(const float* __restrict__ h2,
                                               const float* __restrict__ as2,
                                               const float* __restrict__ ad2,
                                               const int* __restrict__ off,
                                               const int* __restrict__ csr_src,
                                               const float* __restrict__ b2,
                                               unsigned* __restrict__ poolbuf) {
    int n = blockIdx.x, t = threadIdx.x;
    int w = t >> 6, l = t & 63;
    int col0 = l * 2;
    int e0 = off[n], e1 = off[n + 1];
    float adv = ad2[n];
    __shared__ int ssrc[64];
    __shared__ float sw[64];
    __shared__ float red[2][64][2];
    __shared__ float ssum;
    float acc0 = 0.f, acc1 = 0.f;
    float ps = 0.f;
    for (int base = e0; base < e1; base += 64) {
        int c = min(64, e1 - base);
        __syncthreads();
        if (t < c) {
            int s = csr_src[base + t];
            ssrc[t] = s;
            float wv = __expf(lrelu(as2[s] + adv));
            sw[t] = wv;
            ps += wv;
        }
        __syncthreads();
        int j = w;
        for (; j + 8 <= c; j += 8) {
            const float2 v0 = *(const float2*)(h2 + (size_t)ssrc[j] * D2 + col0);
            const float2 v1 = *(const float2*)(h2 + (size_t)ssrc[j + 2] * D2 + col0);
            const float2 v2 = *(const float2*)(h2 + (size_t)ssrc[j + 4] * D2 + col0);
            const float2 v3 = *(const float2*)(h2 + (size_t)ssrc[j + 6] * D2 + col0);
            acc0 += v0.x * sw[j];     acc1 += v0.y * sw[j];
            acc0 += v1.x * sw[j + 2]; acc1 += v1.y * sw[j + 2];
            acc0 += v2.x * sw[j + 4]; acc1 += v2.y * sw[j + 4];
            acc0 += v3.x * sw[j + 6]; acc1 += v3.y * sw[j + 6];
        }
        for (; j < c; j += 2) {
            const float2 v = *(const float2*)(h2 + (size_t)ssrc[j] * D2 + col0);
            acc0 += v.x * sw[j];
            acc1 += v.y * sw[j];
        }
    }
    // ps lives in wave 0 only (staging lanes t<64)
    if (t < 64) {
#pragma unroll
        for (int o = 32; o > 0; o >>= 1) ps += __shfl_down(ps, o);
        if (t == 0) ssum = ps;
    }
    red[w][l][0] = acc0;
    red[w][l][1] = acc1;
    __syncthreads();
    if (t < 64) {
        float r0 = red[0][l][0] + red[1][l][0];
        float r1 = red[0][l][1] + red[1][l][1];
        float inv = 1.f / ssum;
        int gidx = (int)(((long long)n * GG) / NN);   // batch[n] = n*G//N
        float v0 = fmaxf(r0 * inv + b2[col0], 0.f);
        float v1 = fmaxf(r1 * inv + b2[col0 + 1], 0.f);
        atomicMax(&poolbuf[gidx * D2 + col0], fenc(v0));
        atomicMax(&poolbuf[gidx * D2 + col0 + 1], fenc(v1));
    }
}

// ===== GEMM1 (MFMA bf16x3, B staged in LDS): h1 = ELU(xagg_h @ W1_h + b1) =====
__global__ __launch_bounds__(256) void k_gemm1m(const ushort_t* __restrict__ xgh,
                                                const ushort_t* __restrict__ xgl,
                                                const ushort_t* __restrict__ W1Th,
                                                const ushort_t* __restrict__ W1Tl,
                                                const float* __restrict__ b1,
                                                ushort_t* __restrict__ h1hi,
                                                ushort_t* __restrict__ h1lo) {
    int h = blockIdx.y;
    int rb = blockIdx.x * 128;
    int tid = threadIdx.x;
    int w = tid >> 6, l = tid & 63;
    int m = l & 15, g = l >> 4;
    int r0 = rb + w * 32 + m;
    int r1 = r0 + 16;
    bool ok0 = (r0 < NN), ok1 = (r1 < NN);
    const ushort_t* xh = xgh + (size_t)h * NN * 128;
    const ushort_t* xl = xgl + (size_t)h * NN * 128;
    const ushort_t* Bhg = W1Th + (size_t)h * 128 * 128;
    const ushort_t* Blg = W1Tl + (size_t)h * 128 * 128;
    const short8v z8 = {0, 0, 0, 0, 0, 0, 0, 0};
    __shared__ __align__(16) ushort_t BsH[128 * 40];   // row stride 40 hw = 80B
    __shared__ __align__(16) ushort_t BsL[128 * 40];
    f32x4 acc0[8], acc1[8];
#pragma unroll
    for (int j = 0; j < 8; j++) {
        acc0[j] = (f32x4){0.f, 0.f, 0.f, 0.f};
        acc1[j] = (f32x4){0.f, 0.f, 0.f, 0.f};
    }
    for (int k0i = 0; k0i < 4; k0i++) {
        int k0 = k0i * 32;
        __syncthreads();
        int ka = k0 + g * 8;
        short8v a0h = ok0 ? *(const short8v*)(xh + (size_t)r0 * 128 + ka) : z8;
        short8v a0l = ok0 ? *(const short8v*)(xl + (size_t)r0 * 128 + ka) : z8;
        short8v a1h = ok1 ? *(const short8v*)(xh + (size_t)r1 * 128 + ka) : z8;
        short8v a1l = ok1 ? *(const short8v*)(xl + (size_t)r1 * 128 + ka) : z8;
#pragma unroll
        for (int it = 0; it < 2; it++) {
            int idx = tid + it * 256;
            int c = idx >> 2, q = idx & 3;
            size_t go = (size_t)c * 128 + k0 + q * 8;
            int lo_off = c * 40 + q * 8;
            *(short8v*)(&BsH[lo_off]) = *(const short8v*)(Bhg + go);
            *(short8v*)(&BsL[lo_off]) = *(const short8v*)(Blg + go);
        }
        __syncthreads();
#pragma unroll
        for (int j = 0; j < 8; j++) {
            int c = j * 16 + m;
            short8v bh = *(const short8v*)(&BsH[c * 40 + g * 8]);
            short8v bl = *(const short8v*)(&BsL[c * 40 + g * 8]);
            acc0[j] = __builtin_amdgcn_mfma_f32_16x16x32_bf16(a0h, bh, acc0[j], 0, 0, 0);
            acc1[j] = __builtin_amdgcn_mfma_f32_16x16x32_bf16(a1h, bh, acc1[j], 0, 0, 0);
            acc0[j] = __builtin_amdgcn_mfma_f32_16x16x32_bf16(a0h, bl, acc0[j], 0, 0, 0);
            acc1[j] = __builtin_amdgcn_mfma_f32_16x16x32_bf16(a1h, bl, acc1[j], 0, 0, 0);
            acc0[j] = __builtin_amdgcn_mfma_f32_16x16x32_bf16(a0l, bh, acc0[j], 0, 0, 0);
            acc1[j] = __builtin_amdgcn_mfma_f32_16x16x32_bf16(a1l, bh, acc1[j], 0, 0, 0);
        }
    }
    ushort_t* Hh = h1hi + (size_t)h * NN * 128;
    ushort_t* Hl = h1lo + (size_t)h * NN * 128;
#pragma unroll
    for (int j = 0; j < 8; j++) {
        int c = j * 16 + m;
        float bv = (c < FIN) ? b1[h * FIN + c] : 0.f;
#pragma unroll
        for (int r = 0; r < 4; r++) {
            int orow0 = rb + w * 32 + g * 4 + r;
            int orow1 = orow0 + 16;
            if (orow0 < NN) {
                float v = acc0[j][r] + bv;
                v = v > 0.f ? v : expm1f(v);
                ushort_t hi = 0, lo = 0;
                if (c < FIN) split2(v, hi, lo);
                Hh[(size_t)orow0 * 128 + c] = hi;
                Hl[(size_t)orow0 * 128 + c] = lo;
            }
            if (orow1 < NN) {
                float v = acc1[j][r] + bv;
                v = v > 0.f ? v : expm1f(v);
                ushort_t hi = 0, lo = 0;
                if (c < FIN) split2(v, hi, lo);
                Hh[(size_t)orow1 * 128 + c] = hi;
                Hl[(size_t)orow1 * 128 + c] = lo;
            }
        }
    }
}

// ===== GEMM2 (MFMA bf16x3, B staged in LDS, fused alpha2): h2 = h1 @ W2 =====
__global__ __launch_bounds__(256) void k_gemm2m(const ushort_t* __restrict__ h1hi,
                                                const ushort_t* __restrict__ h1lo,
                                                const ushort_t* __restrict__ W2Th,
                                                const ushort_t* __restrict__ W2Tl,
                                                const float* __restrict__ aS2,
                                                const float* __restrict__ aD2,
                                                float* __restrict__ h2,
                                                float* __restrict__ as2,
                                                float* __restrict__ ad2) {
    int rb = blockIdx.x * 128;
    int tid = threadIdx.x;
    int w = tid >> 6, l = tid & 63;
    int m = l & 15, g = l >> 4;
    int r0 = rb + w * 32 + m;
    int r1 = r0 + 16;
    bool ok0 = (r0 < NN), ok1 = (r1 < NN);
    const short8v z8 = {0, 0, 0, 0, 0, 0, 0, 0};
    __shared__ __align__(16) ushort_t BsH[128 * 40];
    __shared__ __align__(16) ushort_t BsL[128 * 40];
    f32x4 acc0[8], acc1[8];
#pragma unroll
    for (int j = 0; j < 8; j++) {
        acc0[j] = (f32x4){0.f, 0.f, 0.f, 0.f};
        acc1[j] = (f32x4){0.f, 0.f, 0.f, 0.f};
    }
    for (int k0i = 0; k0i < 12; k0i++) {
        int k0 = k0i * 32;
        __syncthreads();
        int hh = k0 >> 7;
        int kc = (k0 & 127) + g * 8;
        size_t a0o = ((size_t)hh * NN + (size_t)(ok0 ? r0 : 0)) * 128 + kc;
        size_t a1o = ((size_t)hh * NN + (size_t)(ok1 ? r1 : 0)) * 128 + kc;
        short8v a0h = ok0 ? *(const short8v*)(h1hi + a0o) : z8;
        short8v a0l = ok0 ? *(const short8v*)(h1lo + a0o) : z8;
        short8v a1h = ok1 ? *(const short8v*)(h1hi + a1o) : z8;
        short8v a1l = ok1 ? *(const short8v*)(h1lo + a1o) : z8;
#pragma unroll
        for (int it = 0; it < 2; it++) {
            int idx = tid + it * 256;
            int c = idx >> 2, q = idx & 3;
            size_t go = (size_t)c * 384 + k0 + q * 8;
            int lo_off = c * 40 + q * 8;
            *(short8v*)(&BsH[lo_off]) = *(const short8v*)(W2Th + go);
            *(short8v*)(&BsL[lo_off]) = *(const short8v*)(W2Tl + go);
        }
        __syncthreads();
#pragma unroll
        for (int j = 0; j < 8; j++) {
            int c = j * 16 + m;
            short8v bh = *(const short8v*)(&BsH[c * 40 + g * 8]);
            short8v bl = *(const short8v*)(&BsL[c * 40 + g * 8]);
            acc0[j] = __builtin_amdgcn_mfma_f32_16x16x32_bf16(a0h, bh, acc0[j], 0, 0, 0);
            acc1[j] = __builtin_amdgcn_mfma_f32_16x16x32_bf16(a1h, bh, acc1[j], 0, 0, 0);
            acc0[j] = __builtin_amdgcn_mfma_f32_16x16x32_bf16(a0h, bl, acc0[j], 0, 0, 0);
            acc1[j] = __builtin_amdgcn_mfma_f32_16x16x32_bf16(a1h, bl, acc1[j], 0, 0, 0);
            acc0[j] = __builtin_amdgcn_mfma_f32_16x16x32_bf16(a0l, bh, acc0[j], 0, 0, 0);
            acc1[j] = __builtin_amdgcn_mfma_f32_16x16x32_bf16(a1l, bh, acc1[j], 0, 0, 0);
        }
    }
#pragma unroll
    for (int j = 0; j < 8; j++) {
        int c = j * 16 + m;
#pragma unroll
        for (int r = 0; r < 4; r++) {
            int orow0 = rb + w * 32 + g * 4 + r;
            int orow1 = orow0 + 16;
            if (orow0 < NN) h2[(size_t)orow0 * D2 + c] = acc0[j][r];
            if (orow1 < NN) h2[(size_t)orow1 * D2 + c] = acc1[j][r];
        }
    }
    // fused alpha2: per output row, dot with aS2/aD2 over 128 cols.
    float sv[8], dv[8];
#pragma unroll
    for (int j = 0; j < 8; j++) {
        sv[j] = aS2[j * 16 + m];
        dv[j] = aD2[j * 16 + m];
    }
#pragma unroll
    for (int r = 0; r < 4; r++) {
        float s0 = 0.f, d0 = 0.f, s1 = 0.f, d1 = 0.f;
#pragma unroll
        for (int j = 0; j < 8; j++) {
            s0 += acc0[j][r] * sv[j];
            d0 += acc0[j][r] * dv[j];
            s1 += acc1[j][r] * sv[j];
            d1 += acc1[j][r] * dv[j];
        }
#pragma unroll
        for (int o = 1; o < 16; o <<= 1) {
            s0 += __shfl_xor(s0, o);
            d0 += __shfl_xor(d0, o);
            s1 += __shfl_xor(s1, o);
            d1 += __shfl_xor(d1, o);
        }
        int orow0 = rb + w * 32 + g * 4 + r;
        int orow1 = orow0 + 16;
        if (m == 0) {
            if (orow0 < NN) { as2[orow0] = s0; ad2[orow0] = d0; }
            if (orow1 < NN) { as2[orow1] = s1; ad2[orow1] = d1; }
        }
    }
}

// ===== MLP head =====
__global__ __launch_bounds__(128) void k_mlp(const unsigned* __restrict__ poolbuf,
                                             const float* __restrict__ Wg,
                                             const float* __restrict__ bg,
                                             const float* __restrict__ Wf1,
                                             const float* __restrict__ bf1,
                                             const float* __restrict__ Wf2,
                                             const float* __restrict__ bf2,
                                             const float* __restrict__ Wo,
                                             const float* __restrict__ bo,
                                             float* __restrict__ out) {
    int g = blockIdx.x;
    int t = threadIdx.x;
    __shared__ float pool[D2];
    __shared__ float a1[64];
    __shared__ float a2[32];
    __shared__ float a3[16];
    pool[t] = fdec(poolbuf[g * D2 + t]);
    __syncthreads();
    if (t < 64) {
        float acc = bg[t];
        for (int k = 0; k < D2; k++) acc += pool[k] * Wg[k * 64 + t];
        a1[t] = fmaxf(acc, 0.f);
    }
    __syncthreads();
    if (t < 32) {
        float acc = bf1[t];
        for (int k = 0; k < 64; k++) acc += a1[k] * Wf1[k * 32 + t];
        a2[t] = fmaxf(acc, 0.f);
    }
    __syncthreads();
    if (t < 16) {
        float acc = bf2[t];
        for (int k = 0; k < 32; k++) acc += a2[k] * Wf2[k * 16 + t];
        a3[t] = fmaxf(acc, 0.f);
    }
    __syncthreads();
    if (t == 0) {
        float acc = bo[0];
        for (int k = 0; k < 16; k++) acc += a3[k] * Wo[k];
        out[g] = acc;
    }
}

extern "C" void kernel_launch(void* const* d_in, const int* in_sizes, int n_in,
                              void* d_out, int out_size, void* d_ws, size_t ws_size,
                              hipStream_t stream) {
    const float* x = (const float*)d_in[0];
    const int* ei = (const int*)d_in[1];
    const float* W1 = (const float*)d_in[3];
    const float* aS1 = (const float*)d_in[4];
    const float* aD1 = (const float*)d_in[5];
    const float* b1 = (const float*)d_in[6];
    const float* W2 = (const float*)d_in[7];
    const float* aS2 = (const float*)d_in[8];
    const float* aD2 = (const float*)d_in[9];
    const float* b2 = (const float*)d_in[10];
    const float* Wg = (const float*)d_in[11];
    const float* bg = (const float*)d_in[12];
    const float* Wf1 = (const float*)d_in[13];
    const float* bf1 = (const float*)d_in[14];
    const float* Wf2 = (const float*)d_in[15];
    const float* bf2 = (const float*)d_in[16];
    const float* Wo = (const float*)d_in[17];
    const float* bo = (const float*)d_in[18];
    float* out = (float*)d_out;

    const int* src = ei;
    const int* dst = ei + EE;

    char* ws = (char*)d_ws;
    size_t o = 0;
    auto alloc = [&](size_t bytes) -> char* {
        char* p = ws + o;
        o += (bytes + 255) & ~(size_t)255;
        return p;
    };
    float* was = (float*)alloc((size_t)FIN * H1 * 4);
    float* wad = (float*)alloc((size_t)FIN * H1 * 4);
    ushort_t* W1Th = (ushort_t*)alloc((size_t)H1 * 128 * 128 * 2);
    ushort_t* W1Tl = (ushort_t*)alloc((size_t)H1 * 128 * 128 * 2);
    ushort_t* W2Th = (ushort_t*)alloc((size_t)128 * 384 * 2);
    ushort_t* W2Tl = (ushort_t*)alloc((size_t)128 * 384 * 2);
    float* as1 = (float*)alloc((size_t)NN * H1 * 4);
    float* ad1 = (float*)alloc((size_t)NN * H1 * 4);
    int* cnt = (int*)alloc((size_t)NN * 4);
    int* off = (int*)alloc((size_t)(NN + 1) * 4);
    int* cur = (int*)alloc((size_t)NN * 4);
    int* csr_src = (int*)alloc((size_t)EE * 4);
    ushort_t* xgh = (ushort_t*)alloc((size_t)H1 * NN * 128 * 2);
    ushort_t* xgl = (ushort_t*)alloc((size_t)H1 * NN * 128 * 2);
    ushort_t* h1hi = (ushort_t*)alloc((size_t)H1 * NN * 128 * 2);
    ushort_t* h1lo = (ushort_t*)alloc((size_t)H1 * NN * 128 * 2);
    float* h2 = (float*)alloc((size_t)NN * D2 * 4);
    float* as2 = (float*)alloc((size_t)NN * 4);
    float* ad2 = (float*)alloc((size_t)NN * 4);
    unsigned* poolbuf = (unsigned*)alloc((size_t)GG * D2 * 4);
    (void)ws_size;

    hipMemsetAsync(cnt, 0, (size_t)NN * 4, stream);
    hipMemsetAsync(cur, 0, (size_t)NN * 4, stream);
    hipMemsetAsync(poolbuf, 0, (size_t)GG * D2 * 4, stream);

    const int EB = (EE + 255) / 256;

    k_wa<<<(2 * FIN * H1 + 255) / 256, 256, 0, stream>>>(W1, aS1, aD1, was, wad);
    k_prep1m<<<(H1 * 128 * 128 + 255) / 256, 256, 0, stream>>>(W1, W1Th, W1Tl);
    k_prep2m<<<(128 * 384 + 255) / 256, 256, 0, stream>>>(W2, W2Th, W2Tl);
    k_alpha1x<<<(NN + 3) / 4, 256, 0, stream>>>(x, was, wad, as1, ad1);
    k_count<<<EB, 256, 0, stream>>>(dst, cnt);
    k_scan<<<1, 1024, 0, stream>>>(cnt, off);
    k_scatter<<<EB, 256, 0, stream>>>(src, dst, off, cur, csr_src);
    k_aggx<<<NN, 128, 0, stream>>>(x, as1, ad1, off, csr_src, xgh, xgl);
    k_gemm1m<<<dim3((NN + 127) / 128, H1), 256, 0, stream>>>(xgh, xgl, W1Th, W1Tl, b1, h1hi, h1lo);
    k_gemm2m<<<(NN + 127) / 128, 256, 0, stream>>>(h1hi, h1lo, W2Th, W2Tl, aS2, aD2, h2, as2, ad2);
    k_agg2f<<<NN, 128, 0, stream>>>(h2, as2, ad2, off, csr_src, b2, poolbuf);
    k_mlp<<<GG, 128, 0, stream>>>(poolbuf, Wg, bg, Wf1, bf1, Wf2, bf2, Wo, bo, out);
}

// Round 18
// 277.867 us; speedup vs baseline: 1.1679x; 1.0424x over previous
//
#include <hip/hip_runtime.h>

#define NN 20000
#define EE 660000      // 640000 + 20000 self loops
#define GG 64
#define FIN 114
#define H1 3
#define F1 342         // H1*FIN
#define D2 128
#define NEG 0.2f

typedef __attribute__((ext_vector_type(8))) short short8v;
typedef __attribute__((ext_vector_type(4))) float f32x4;
typedef unsigned short ushort_t;

__device__ inline unsigned fenc(float f) {
    unsigned u = __float_as_uint(f);
    return (u & 0x80000000u) ? ~u : (u | 0x80000000u);
}
__device__ inline float fdec(unsigned u) {
    return (u & 0x80000000u) ? __uint_as_float(u & 0x7FFFFFFFu) : __uint_as_float(~u);
}
__device__ inline float lrelu(float x) { return x > 0.f ? x : NEG * x; }

// fp32 -> bf16 hi (truncate) + bf16 lo (RNE of residual); x ≈ hi + lo to ~2^-17
__device__ inline void split2(float x, ushort_t& hi, ushort_t& lo) {
    unsigned u = __float_as_uint(x);
    unsigned uh = u & 0xFFFF0000u;
    hi = (ushort_t)(uh >> 16);
    float r = x - __uint_as_float(uh);
    unsigned v = __float_as_uint(r);
    unsigned vh = (v + 0x7FFFu + ((v >> 16) & 1u)) & 0xFFFF0000u;
    lo = (ushort_t)(vh >> 16);
}

// ===== fold a_src/a_dst through W1 =====
__global__ void k_wa(const float* __restrict__ W1, const float* __restrict__ aS,
                     const float* __restrict__ aD, float* __restrict__ was,
                     float* __restrict__ wad) {
    int tid = blockIdx.x * 256 + threadIdx.x;
    if (tid >= 2 * FIN * H1) return;
    int which = tid >= FIN * H1;
    int i = which ? tid - FIN * H1 : tid;
    int k = i / H1, h = i % H1;
    const float* a = which ? aD : aS;
    float s = 0.f;
    for (int d = 0; d < FIN; d++) s += W1[k * F1 + h * FIN + d] * a[h * FIN + d];
    (which ? wad : was)[i] = s;
}

// ===== W1 prep: W1T[h][c][k] hi/lo bf16, c,k in [0,128) zero-padded =====
__global__ void k_prep1m(const float* __restrict__ W1, ushort_t* __restrict__ W1Th,
                         ushort_t* __restrict__ W1Tl) {
    int tid = blockIdx.x * 256 + threadIdx.x;
    if (tid >= H1 * 128 * 128) return;
    int h = tid / (128 * 128);
    int rem = tid & (128 * 128 - 1);
    int c = rem >> 7, k = rem & 127;
    float v = (c < FIN && k < FIN) ? W1[k * F1 + h * FIN + c] : 0.f;
    ushort_t hi, lo;
    split2(v, hi, lo);
    W1Th[tid] = hi;
    W1Tl[tid] = lo;
}

// ===== W2 prep: W2T[c][hk] hi/lo bf16, hk = h*128+k (k zero-padded) =====
__global__ void k_prep2m(const float* __restrict__ W2, ushort_t* __restrict__ W2Th,
                         ushort_t* __restrict__ W2Tl) {
    int tid = blockIdx.x * 256 + threadIdx.x;
    if (tid >= 128 * 384) return;
    int c = tid / 384;
    int hk = tid - c * 384;
    int h = hk >> 7, k = hk & 127;
    float v = (k < FIN) ? W2[(h * FIN + k) * D2 + c] : 0.f;
    ushort_t hi, lo;
    split2(v, hi, lo);
    W2Th[tid] = hi;
    W2Tl[tid] = lo;
}

// ===== as1/ad1 = x @ was/wad =====
__global__ __launch_bounds__(256) void k_alpha1x(const float* __restrict__ x,
                                                 const float* __restrict__ was,
                                                 const float* __restrict__ wad,
                                                 float* __restrict__ as1,
                                                 float* __restrict__ ad1) {
    int n = blockIdx.x * 4 + (threadIdx.x >> 6);
    int l = threadIdx.x & 63;
    if (n >= NN) return;
    float x0 = x[n * FIN + l];
    float x1 = (l < FIN - 64) ? x[n * FIN + 64 + l] : 0.f;
    float s[H1], d[H1];
#pragma unroll
    for (int h = 0; h < H1; h++) {
        float w0s = was[l * H1 + h], w0d = wad[l * H1 + h];
        float w1s = (l < FIN - 64) ? was[(64 + l) * H1 + h] : 0.f;
        float w1d = (l < FIN - 64) ? wad[(64 + l) * H1 + h] : 0.f;
        s[h] = x0 * w0s + x1 * w1s;
        d[h] = x0 * w0d + x1 * w1d;
    }
#pragma unroll
    for (int o = 32; o > 0; o >>= 1) {
#pragma unroll
        for (int h = 0; h < H1; h++) {
            s[h] += __shfl_down(s[h], o);
            d[h] += __shfl_down(d[h], o);
        }
    }
    if (l == 0) {
#pragma unroll
        for (int h = 0; h < H1; h++) {
            as1[n * H1 + h] = s[h];
            ad1[n * H1 + h] = d[h];
        }
    }
}

// ===================== CSR build =====================
__global__ void k_count(const int* __restrict__ dst, int* __restrict__ cnt) {
    int e = blockIdx.x * 256 + threadIdx.x;
    if (e < EE) atomicAdd(&cnt[dst[e]], 1);
}

__global__ __launch_bounds__(1024) void k_scan(const int* __restrict__ cnt,
                                               int* __restrict__ off) {
    __shared__ int part[1024];
    int t = threadIdx.x;
    const int CH = 20;
    int loc[CH];
    int s = 0;
    int base = t * CH;
    for (int i = 0; i < CH; i++) {
        int idx = base + i;
        int v = (idx < NN) ? cnt[idx] : 0;
        loc[i] = s;
        s += v;
    }
    part[t] = s;
    __syncthreads();
    for (int d = 1; d < 1024; d <<= 1) {
        int v = (t >= d) ? part[t - d] : 0;
        __syncthreads();
        part[t] += v;
        __syncthreads();
    }
    int pre = (t == 0) ? 0 : part[t - 1];
    for (int i = 0; i < CH; i++) {
        int idx = base + i;
        if (idx < NN) off[idx] = pre + loc[i];
    }
    if (t == 1023) off[NN] = part[1023];
}

__global__ void k_scatter(const int* __restrict__ src, const int* __restrict__ dst,
                          const int* __restrict__ off, int* __restrict__ cur,
                          int* __restrict__ csr_src) {
    int e = blockIdx.x * 256 + threadIdx.x;
    if (e < EE) {
        int d = dst[e];
        int pos = off[d] + atomicAdd(&cur[d], 1);
        csr_src[pos] = src[e];
    }
}

// ===== layer-1: fused softmax+aggregate of x -> xg hi/lo bf16 [3][N][128] =====
__global__ __launch_bounds__(128) void k_aggx(const float* __restrict__ x,
                                              const float* __restrict__ as1,
                                              const float* __restrict__ ad1,
                                              const int* __restrict__ off,
                                              const int* __restrict__ csr_src,
                                              ushort_t* __restrict__ xgh,
                                              ushort_t* __restrict__ xgl) {
    int n = blockIdx.x, t = threadIdx.x;
    int e0 = off[n], e1 = off[n + 1];
    float adv0 = ad1[n * H1 + 0], adv1 = ad1[n * H1 + 1], adv2 = ad1[n * H1 + 2];
    __shared__ int ssrc[64];
    __shared__ float sw[64][H1];
    __shared__ float red[64][H1];
    float acc0 = 0.f, acc1 = 0.f, acc2 = 0.f;
    float ps0 = 0.f, ps1 = 0.f, ps2 = 0.f;
    for (int base = e0; base < e1; base += 64) {
        int c = min(64, e1 - base);
        __syncthreads();
        if (t < c) {
            int s = csr_src[base + t];
            ssrc[t] = s;
            float w0 = __expf(lrelu(as1[s * H1 + 0] + adv0));
            float w1 = __expf(lrelu(as1[s * H1 + 1] + adv1));
            float w2 = __expf(lrelu(as1[s * H1 + 2] + adv2));
            sw[t][0] = w0; sw[t][1] = w1; sw[t][2] = w2;
            ps0 += w0; ps1 += w1; ps2 += w2;
        }
        __syncthreads();
        if (t < FIN) {
            int j = 0;
            for (; j + 4 <= c; j += 4) {
                int s0 = ssrc[j + 0], s1 = ssrc[j + 1];
                int s2 = ssrc[j + 2], s3 = ssrc[j + 3];
                float v0 = x[(size_t)s0 * FIN + t];
                float v1 = x[(size_t)s1 * FIN + t];
                float v2 = x[(size_t)s2 * FIN + t];
                float v3 = x[(size_t)s3 * FIN + t];
                acc0 += v0 * sw[j + 0][0]; acc1 += v0 * sw[j + 0][1]; acc2 += v0 * sw[j + 0][2];
                acc0 += v1 * sw[j + 1][0]; acc1 += v1 * sw[j + 1][1]; acc2 += v1 * sw[j + 1][2];
                acc0 += v2 * sw[j + 2][0]; acc1 += v2 * sw[j + 2][1]; acc2 += v2 * sw[j + 2][2];
                acc0 += v3 * sw[j + 3][0]; acc1 += v3 * sw[j + 3][1]; acc2 += v3 * sw[j + 3][2];
            }
            for (; j < c; j++) {
                float xv = x[(size_t)ssrc[j] * FIN + t];
                acc0 += xv * sw[j][0];
                acc1 += xv * sw[j][1];
                acc2 += xv * sw[j][2];
            }
        }
    }
    __syncthreads();
    if (t < 64) { red[t][0] = ps0; red[t][1] = ps1; red[t][2] = ps2; }
    __syncthreads();
    for (int sr = 32; sr > 0; sr >>= 1) {
        if (t < sr) {
            red[t][0] += red[t + sr][0];
            red[t][1] += red[t + sr][1];
            red[t][2] += red[t + sr][2];
        }
        __syncthreads();
    }
    float i0 = 1.f / red[0][0], i1 = 1.f / red[0][1], i2 = 1.f / red[0][2];
    float v0 = (t < FIN) ? acc0 * i0 : 0.f;
    float v1 = (t < FIN) ? acc1 * i1 : 0.f;
    float v2 = (t < FIN) ? acc2 * i2 : 0.f;
    ushort_t hi, lo;
    split2(v0, hi, lo);
    xgh[(size_t)0 * NN * 128 + n * 128 + t] = hi;
    xgl[(size_t)0 * NN * 128 + n * 128 + t] = lo;
    split2(v1, hi, lo);
    xgh[(size_t)1 * NN * 128 + n * 128 + t] = hi;
    xgl[(size_t)1 * NN * 128 + n * 128 + t] = lo;
    split2(v2, hi, lo);
    xgh[(size_t)2 * NN * 128 + n * 128 + t] = hi;
    xgl[(size_t)2 * NN * 128 + n * 128 + t] = lo;
}

// ===== layer-2: fused softmax+aggregate+relu+POOL (r15 structure) =====
__global__ __launch_bounds__(128) void k_agg2f(const float* __restrict__ h2,
                                               const float* __restrict__ as2,
                                               const float* __restrict__ ad2,
                                               const int* __restrict__ off,
                                               const int* __restrict__ csr_src,
                                               const float* __restrict__ b2,
                                               unsigned* __restrict__ poolbuf) {
    int n = blockIdx.x, t = threadIdx.x;
    int e0 = off[n], e1 = off[n + 1];
    float adv = ad2[n];
    __shared__ int ssrc[64];
    __shared__ float sw[64];
    __shared__ float red[64];
    float acc = 0.f, ps = 0.f;
    for (int base = e0; base < e1; base += 64) {
        int c = min(64, e1 - base);
        __syncthreads();
        if (t < c) {
            int s = csr_src[base + t];
            ssrc[t] = s;
            float w = __expf(lrelu(as2[s] + adv));
            sw[t] = w;
            ps += w;
        }
        __syncthreads();
        int j = 0;
        for (; j + 8 <= c; j += 8) {
            float v0 = h2[(size_t)ssrc[j + 0] * D2 + t];
            float v1 = h2[(size_t)ssrc[j + 1] * D2 + t];
            float v2 = h2[(size_t)ssrc[j + 2] * D2 + t];
            float v3 = h2[(size_t)ssrc[j + 3] * D2 + t];
            float v4 = h2[(size_t)ssrc[j + 4] * D2 + t];
            float v5 = h2[(size_t)ssrc[j + 5] * D2 + t];
            float v6 = h2[(size_t)ssrc[j + 6] * D2 + t];
            float v7 = h2[(size_t)ssrc[j + 7] * D2 + t];
            acc += v0 * sw[j + 0]; acc += v1 * sw[j + 1];
            acc += v2 * sw[j + 2]; acc += v3 * sw[j + 3];
            acc += v4 * sw[j + 4]; acc += v5 * sw[j + 5];
            acc += v6 * sw[j + 6]; acc += v7 * sw[j + 7];
        }
        for (; j < c; j++) acc += h2[(size_t)ssrc[j] * D2 + t] * sw[j];
    }
    __syncthreads();
    if (t < 64) red[t] = ps;
    __syncthreads();
    for (int sr = 32; sr > 0; sr >>= 1) {
        if (t < sr) red[t] += red[t + sr];
        __syncthreads();
    }
    float v = fmaxf(acc / red[0] + b2[t], 0.f);
    int g = (int)(((long long)n * GG) / NN);   // batch[n] = n*G//N
    atomicMax(&poolbuf[g * D2 + t], fenc(v));
}

// ===== GEMM1 (MFMA bf16x3, B staged in LDS): h1 = ELU(xagg_h @ W1_h + b1) =====
__global__ __launch_bounds__(256) void k_gemm1m(const ushort_t* __restrict__ xgh,
                                                const ushort_t* __restrict__ xgl,
                                                const ushort_t* __restrict__ W1Th,
                                                const ushort_t* __restrict__ W1Tl,
                                                const float* __restrict__ b1,
                                                ushort_t* __restrict__ h1hi,
                                                ushort_t* __restrict__ h1lo) {
    int h = blockIdx.y;
    int rb = blockIdx.x * 128;
    int tid = threadIdx.x;
    int w = tid >> 6, l = tid & 63;
    int m = l & 15, g = l >> 4;
    int r0 = rb + w * 32 + m;
    int r1 = r0 + 16;
    bool ok0 = (r0 < NN), ok1 = (r1 < NN);
    const ushort_t* xh = xgh + (size_t)h * NN * 128;
    const ushort_t* xl = xgl + (size_t)h * NN * 128;
    const ushort_t* Bhg = W1Th + (size_t)h * 128 * 128;
    const ushort_t* Blg = W1Tl + (size_t)h * 128 * 128;
    const short8v z8 = {0, 0, 0, 0, 0, 0, 0, 0};
    __shared__ __align__(16) ushort_t BsH[128 * 40];   // row stride 40 hw = 80B
    __shared__ __align__(16) ushort_t BsL[128 * 40];
    f32x4 acc0[8], acc1[8];
#pragma unroll
    for (int j = 0; j < 8; j++) {
        acc0[j] = (f32x4){0.f, 0.f, 0.f, 0.f};
        acc1[j] = (f32x4){0.f, 0.f, 0.f, 0.f};
    }
    for (int k0i = 0; k0i < 4; k0i++) {
        int k0 = k0i * 32;
        __syncthreads();
        int ka = k0 + g * 8;
        short8v a0h = ok0 ? *(const short8v*)(xh + (size_t)r0 * 128 + ka) : z8;
        short8v a0l = ok0 ? *(const short8v*)(xl + (size_t)r0 * 128 + ka) : z8;
        short8v a1h = ok1 ? *(const short8v*)(xh + (size_t)r1 * 128 + ka) : z8;
        short8v a1l = ok1 ? *(const short8v*)(xl + (size_t)r1 * 128 + ka) : z8;
#pragma unroll
        for (int it = 0; it < 2; it++) {
            int idx = tid + it * 256;
            int c = idx >> 2, q = idx & 3;
            size_t go = (size_t)c * 128 + k0 + q * 8;
            int lo_off = c * 40 + q * 8;
            *(short8v*)(&BsH[lo_off]) = *(const short8v*)(Bhg + go);
            *(short8v*)(&BsL[lo_off]) = *(const short8v*)(Blg + go);
        }
        __syncthreads();
#pragma unroll
        for (int j = 0; j < 8; j++) {
            int c = j * 16 + m;
            short8v bh = *(const short8v*)(&BsH[c * 40 + g * 8]);
            short8v bl = *(const short8v*)(&BsL[c * 40 + g * 8]);
            acc0[j] = __builtin_amdgcn_mfma_f32_16x16x32_bf16(a0h, bh, acc0[j], 0, 0, 0);
            acc1[j] = __builtin_amdgcn_mfma_f32_16x16x32_bf16(a1h, bh, acc1[j], 0, 0, 0);
            acc0[j] = __builtin_amdgcn_mfma_f32_16x16x32_bf16(a0h, bl, acc0[j], 0, 0, 0);
            acc1[j] = __builtin_amdgcn_mfma_f32_16x16x32_bf16(a1h, bl, acc1[j], 0, 0, 0);
            acc0[j] = __builtin_amdgcn_mfma_f32_16x16x32_bf16(a0l, bh, acc0[j], 0, 0, 0);
            acc1[j] = __builtin_amdgcn_mfma_f32_16x16x32_bf16(a1l, bh, acc1[j], 0, 0, 0);
        }
    }
    ushort_t* Hh = h1hi + (size_t)h * NN * 128;
    ushort_t* Hl = h1lo + (size_t)h * NN * 128;
#pragma unroll
    for (int j = 0; j < 8; j++) {
        int c = j * 16 + m;
        float bv = (c < FIN) ? b1[h * FIN + c] : 0.f;
#pragma unroll
        for (int r = 0; r < 4; r++) {
            int orow0 = rb + w * 32 + g * 4 + r;
            int orow1 = orow0 + 16;
            if (orow0 < NN) {
                float v = acc0[j][r] + bv;
                v = v > 0.f ? v : expm1f(v);
                ushort_t hi = 0, lo = 0;
                if (c < FIN) split2(v, hi, lo);
                Hh[(size_t)orow0 * 128 + c] = hi;
                Hl[(size_t)orow0 * 128 + c] = lo;
            }
            if (orow1 < NN) {
                float v = acc1[j][r] + bv;
                v = v > 0.f ? v : expm1f(v);
                ushort_t hi = 0, lo = 0;
                if (c < FIN) split2(v, hi, lo);
                Hh[(size_t)orow1 * 128 + c] = hi;
                Hl[(size_t)orow1 * 128 + c] = lo;
            }
        }
    }
}

// ===== GEMM2 (MFMA bf16x3, B staged in LDS, fused alpha2): h2 = h1 @ W2 =====
__global__ __launch_bounds__(256) void k_gemm2m(const ushort_t* __restrict__ h1hi,
                                                const ushort_t* __restrict__ h1lo,
                                                const ushort_t* __restrict__ W2Th,
                                                const ushort_t* __restrict__ W2Tl,
                                                const float* __restrict__ aS2,
                                                const float* __restrict__ aD2,
                                                float* __restrict__ h2,
                                                float* __restrict__ as2,
                                                float* __restrict__ ad2) {
    int rb = blockIdx.x * 128;
    int tid = threadIdx.x;
    int w = tid >> 6, l = tid & 63;
    int m = l & 15, g = l >> 4;
    int r0 = rb + w * 32 + m;
    int r1 = r0 + 16;
    bool ok0 = (r0 < NN), ok1 = (r1 < NN);
    const short8v z8 = {0, 0, 0, 0, 0, 0, 0, 0};
    __shared__ __align__(16) ushort_t BsH[128 * 40];
    __shared__ __align__(16) ushort_t BsL[128 * 40];
    f32x4 acc0[8], acc1[8];
#pragma unroll
    for (int j = 0; j < 8; j++) {
        acc0[j] = (f32x4){0.f, 0.f, 0.f, 0.f};
        acc1[j] = (f32x4){0.f, 0.f, 0.f, 0.f};
    }
    for (int k0i = 0; k0i < 12; k0i++) {
        int k0 = k0i * 32;
        __syncthreads();
        int hh = k0 >> 7;
        int kc = (k0 & 127) + g * 8;
        size_t a0o = ((size_t)hh * NN + (size_t)(ok0 ? r0 : 0)) * 128 + kc;
        size_t a1o = ((size_t)hh * NN + (size_t)(ok1 ? r1 : 0)) * 128 + kc;
        short8v a0h = ok0 ? *(const short8v*)(h1hi + a0o) : z8;
        short8v a0l = ok0 ? *(const short8v*)(h1lo + a0o) : z8;
        short8v a1h = ok1 ? *(const short8v*)(h1hi + a1o) : z8;
        short8v a1l = ok1 ? *(const short8v*)(h1lo + a1o) : z8;
#pragma unroll
        for (int it = 0; it < 2; it++) {
            int idx = tid + it * 256;
            int c = idx >> 2, q = idx & 3;
            size_t go = (size_t)c * 384 + k0 + q * 8;
            int lo_off = c * 40 + q * 8;
            *(short8v*)(&BsH[lo_off]) = *(const short8v*)(W2Th + go);
            *(short8v*)(&BsL[lo_off]) = *(const short8v*)(W2Tl + go);
        }
        __syncthreads();
#pragma unroll
        for (int j = 0; j < 8; j++) {
            int c = j * 16 + m;
            short8v bh = *(const short8v*)(&BsH[c * 40 + g * 8]);
            short8v bl = *(const short8v*)(&BsL[c * 40 + g * 8]);
            acc0[j] = __builtin_amdgcn_mfma_f32_16x16x32_bf16(a0h, bh, acc0[j], 0, 0, 0);
            acc1[j] = __builtin_amdgcn_mfma_f32_16x16x32_bf16(a1h, bh, acc1[j], 0, 0, 0);
            acc0[j] = __builtin_amdgcn_mfma_f32_16x16x32_bf16(a0h, bl, acc0[j], 0, 0, 0);
            acc1[j] = __builtin_amdgcn_mfma_f32_16x16x32_bf16(a1h, bl, acc1[j], 0, 0, 0);
            acc0[j] = __builtin_amdgcn_mfma_f32_16x16x32_bf16(a0l, bh, acc0[j], 0, 0, 0);
            acc1[j] = __builtin_amdgcn_mfma_f32_16x16x32_bf16(a1l, bh, acc1[j], 0, 0, 0);
        }
    }
#pragma unroll
    for (int j = 0; j < 8; j++) {
        int c = j * 16 + m;
#pragma unroll
        for (int r = 0; r < 4; r++) {
            int orow0 = rb + w * 32 + g * 4 + r;
            int orow1 = orow0 + 16;
            if (orow0 < NN) h2[(size_t)orow0 * D2 + c] = acc0[j][r];
            if (orow1 < NN) h2[(size_t)orow1 * D2 + c] = acc1[j][r];
        }
    }
    // fused alpha2: per output row, dot with aS2/aD2 over 128 cols.
    float sv[8], dv[8];
#pragma unroll
    for (int j = 0; j < 8; j++) {
        sv[j] = aS2[j * 16 + m];
        dv[j] = aD2[j * 16 + m];
    }
#pragma unroll
    for (int r = 0; r < 4; r++) {
        float s0 = 0.f, d0 = 0.f, s1 = 0.f, d1 = 0.f;
#pragma unroll
        for (int j = 0; j < 8; j++) {
            s0 += acc0[j][r] * sv[j];
            d0 += acc0[j][r] * dv[j];
            s1 += acc1[j][r] * sv[j];
            d1 += acc1[j][r] * dv[j];
        }
#pragma unroll
        for (int o = 1; o < 16; o <<= 1) {
            s0 += __shfl_xor(s0, o);
            d0 += __shfl_xor(d0, o);
            s1 += __shfl_xor(s1, o);
            d1 += __shfl_xor(d1, o);
        }
        int orow0 = rb + w * 32 + g * 4 + r;
        int orow1 = orow0 + 16;
        if (m == 0) {
            if (orow0 < NN) { as2[orow0] = s0; ad2[orow0] = d0; }
            if (orow1 < NN) { as2[orow1] = s1; ad2[orow1] = d1; }
        }
    }
}

// ===== MLP head =====
__global__ __launch_bounds__(128) void k_mlp(const unsigned* __restrict__ poolbuf,
                                             const float* __restrict__ Wg,
                                             const float* __restrict__ bg,
                                             const float* __restrict__ Wf1,
                                             const float* __restrict__ bf1,
                                             const float* __restrict__ Wf2,
                                             const float* __restrict__ bf2,
                                             const float* __restrict__ Wo,
                                             const float* __restrict__ bo,
                                             float* __restrict__ out) {
    int g = blockIdx.x;
    int t = threadIdx.x;
    __shared__ float pool[D2];
    __shared__ float a1[64];
    __shared__ float a2[32];
    __shared__ float a3[16];
    pool[t] = fdec(poolbuf[g * D2 + t]);
    __syncthreads();
    if (t < 64) {
        float acc = bg[t];
        for (int k = 0; k < D2; k++) acc += pool[k] * Wg[k * 64 + t];
        a1[t] = fmaxf(acc, 0.f);
    }
    __syncthreads();
    if (t < 32) {
        float acc = bf1[t];
        for (int k = 0; k < 64; k++) acc += a1[k] * Wf1[k * 32 + t];
        a2[t] = fmaxf(acc, 0.f);
    }
    __syncthreads();
    if (t < 16) {
        float acc = bf2[t];
        for (int k = 0; k < 32; k++) acc += a2[k] * Wf2[k * 16 + t];
        a3[t] = fmaxf(acc, 0.f);
    }
    __syncthreads();
    if (t == 0) {
        float acc = bo[0];
        for (int k = 0; k < 16; k++) acc += a3[k] * Wo[k];
        out[g] = acc;
    }
}

extern "C" void kernel_launch(void* const* d_in, const int* in_sizes, int n_in,
                              void* d_out, int out_size, void* d_ws, size_t ws_size,
                              hipStream_t stream) {
    const float* x = (const float*)d_in[0];
    const int* ei = (const int*)d_in[1];
    const float* W1 = (const float*)d_in[3];
    const float* aS1 = (const float*)d_in[4];
    const float* aD1 = (const float*)d_in[5];
    const float* b1 = (const float*)d_in[6];
    const float* W2 = (const float*)d_in[7];
    const float* aS2 = (const float*)d_in[8];
    const float* aD2 = (const float*)d_in[9];
    const float* b2 = (const float*)d_in[10];
    const float* Wg = (const float*)d_in[11];
    const float* bg = (const float*)d_in[12];
    const float* Wf1 = (const float*)d_in[13];
    const float* bf1 = (const float*)d_in[14];
    const float* Wf2 = (const float*)d_in[15];
    const float* bf2 = (const float*)d_in[16];
    const float* Wo = (const float*)d_in[17];
    const float* bo = (const float*)d_in[18];
    float* out = (float*)d_out;

    const int* src = ei;
    const int* dst = ei + EE;

    char* ws = (char*)d_ws;
    size_t o = 0;
    auto alloc = [&](size_t bytes) -> char* {
        char* p = ws + o;
        o += (bytes + 255) & ~(size_t)255;
        return p;
    };
    float* was = (float*)alloc((size_t)FIN * H1 * 4);
    float* wad = (float*)alloc((size_t)FIN * H1 * 4);
    ushort_t* W1Th = (ushort_t*)alloc((size_t)H1 * 128 * 128 * 2);
    ushort_t* W1Tl = (ushort_t*)alloc((size_t)H1 * 128 * 128 * 2);
    ushort_t* W2Th = (ushort_t*)alloc((size_t)128 * 384 * 2);
    ushort_t* W2Tl = (ushort_t*)alloc((size_t)128 * 384 * 2);
    float* as1 = (float*)alloc((size_t)NN * H1 * 4);
    float* ad1 = (float*)alloc((size_t)NN * H1 * 4);
    int* cnt = (int*)alloc((size_t)NN * 4);
    int* off = (int*)alloc((size_t)(NN + 1) * 4);
    int* cur = (int*)alloc((size_t)NN * 4);
    int* csr_src = (int*)alloc((size_t)EE * 4);
    ushort_t* xgh = (ushort_t*)alloc((size_t)H1 * NN * 128 * 2);
    ushort_t* xgl = (ushort_t*)alloc((size_t)H1 * NN * 128 * 2);
    ushort_t* h1hi = (ushort_t*)alloc((size_t)H1 * NN * 128 * 2);
    ushort_t* h1lo = (ushort_t*)alloc((size_t)H1 * NN * 128 * 2);
    float* h2 = (float*)alloc((size_t)NN * D2 * 4);
    float* as2 = (float*)alloc((size_t)NN * 4);
    float* ad2 = (float*)alloc((size_t)NN * 4);
    unsigned* poolbuf = (unsigned*)alloc((size_t)GG * D2 * 4);
    (void)ws_size;

    hipMemsetAsync(cnt, 0, (size_t)NN * 4, stream);
    hipMemsetAsync(cur, 0, (size_t)NN * 4, stream);
    hipMemsetAsync(poolbuf, 0, (size_t)GG * D2 * 4, stream);

    const int EB = (EE + 255) / 256;

    k_wa<<<(2 * FIN * H1 + 255) / 256, 256, 0, stream>>>(W1, aS1, aD1, was, wad);
    k_prep1m<<<(H1 * 128 * 128 + 255) / 256, 256, 0, stream>>>(W1, W1Th, W1Tl);
    k_prep2m<<<(128 * 384 + 255) / 256, 256, 0, stream>>>(W2, W2Th, W2Tl);
    k_alpha1x<<<(NN + 3) / 4, 256, 0, stream>>>(x, was, wad, as1, ad1);
    k_count<<<EB, 256, 0, stream>>>(dst, cnt);
    k_scan<<<1, 1024, 0, stream>>>(cnt, off);
    k_scatter<<<EB, 256, 0, stream>>>(src, dst, off, cur, csr_src);
    k_aggx<<<NN, 128, 0, stream>>>(x, as1, ad1, off, csr_src, xgh, xgl);
    k_gemm1m<<<dim3((NN + 127) / 128, H1), 256, 0, stream>>>(xgh, xgl, W1Th, W1Tl, b1, h1hi, h1lo);
    k_gemm2m<<<(NN + 127) / 128, 256, 0, stream>>>(h1hi, h1lo, W2Th, W2Tl, aS2, aD2, h2, as2, ad2);
    k_agg2f<<<NN, 128, 0, stream>>>(h2, as2, ad2, off, csr_src, b2, poolbuf);
    k_mlp<<<GG, 128, 0, stream>>>(poolbuf, Wg, bg, Wf1, bf1, Wf2, bf2, Wo, bo, out);
}